// Round 1
// 904.487 us; speedup vs baseline: 1.1115x; 1.1115x over previous
//
#include <hip/hip_runtime.h>
#include <hip/hip_bf16.h>

typedef unsigned short u16;
typedef __attribute__((ext_vector_type(8))) short short8;
typedef __attribute__((ext_vector_type(4))) float f32x4;

#define SD   128
#define SNIN 384
#define SK   48
#define HPAD 136   // 128+8 elems -> row stride 272B (16B-aligned, bank-friendly)
#define FPAD 520   // 512+8 elems

// ws layout (bytes) — packed bf16 weights only (448 KB total)
#define OFF_W1A   0
#define OFF_W1B   32768
#define OFF_W2    131072
#define OFF_W3    163840
#define OFF_WIN   196608
#define OFF_WOUT  327680

__device__ __forceinline__ u16 f2b(float f){
  union { float f; unsigned u; } v; v.f = f;
  unsigned r = (v.u + 0x7FFFu + ((v.u >> 16) & 1u)) >> 16;   // RNE
  return (u16)r;
}
__device__ __forceinline__ short8 ldg8(const u16* p){
  return *reinterpret_cast<const short8*>(p);
}
// pack 8 fp32 (two float4) -> bf16x8 via v_cvt_pk_bf16_f32 (RNE, 4 instrs)
__device__ __forceinline__ short8 pack8(float4 a, float4 b){
  union { unsigned u[4]; short8 s; } r;
  asm("v_cvt_pk_bf16_f32 %0, %1, %2" : "=v"(r.u[0]) : "v"(a.x), "v"(a.y));
  asm("v_cvt_pk_bf16_f32 %0, %1, %2" : "=v"(r.u[1]) : "v"(a.z), "v"(a.w));
  asm("v_cvt_pk_bf16_f32 %0, %1, %2" : "=v"(r.u[2]) : "v"(b.x), "v"(b.y));
  asm("v_cvt_pk_bf16_f32 %0, %1, %2" : "=v"(r.u[3]) : "v"(b.z), "v"(b.w));
  return r.s;
}
__device__ __forceinline__ short8 cvt8(const float* p){
  float4 a = *reinterpret_cast<const float4*>(p);
  float4 b = *reinterpret_cast<const float4*>(p + 4);
  return pack8(a, b);
}

// gelu(x)=0.5*x*(1+erf(x/sqrt2)); odd deg-7 poly of erf on [-3,3], clamped. abs err < 7e-3.
__device__ __forceinline__ float gelu_f(float x){
  float xc = fminf(3.0f, fmaxf(-3.0f, x));
  float u  = xc*xc;
  float p  = fmaf(u, fmaf(u, fmaf(u, -4.81034e-4f, 1.185750e-2f), -1.1877797e-1f), 7.9165011e-1f);
  float t  = xc*p;
  float hx = 0.5f*x;
  return fmaf(t, hx, hx);
}

// ---------------- prep: fp32 weights -> bf16 MFMA B-fragment-linear layout ----------------
// B-frag (16x16x32): lane holds B[k=(lane>>4)*8+j][n=nt*16+(lane&15)], j=0..7.
// Frag order: ((ks*NT + nt)*64 + lane)*8 elems -> 16B contiguous per lane.
__global__ __launch_bounds__(256) void prep_pack(
    const float* __restrict__ W1, const float* __restrict__ W2, const float* __restrict__ W3,
    const float* __restrict__ Win, const float* __restrict__ Wout, u16* __restrict__ ws)
{
  int t = blockIdx.x*256 + threadIdx.x;   // 28672 frag-lanes total
  const float* src; int stride, rowoff, NT; u16* dst; int local;
  if (t < 2048)       { src=W1;  stride=SD;  rowoff=0;   NT=8;  dst=ws+OFF_W1A/2;  local=t;       }
  else if (t < 8192)  { src=W1;  stride=SD;  rowoff=128; NT=8;  dst=ws+OFF_W1B/2;  local=t-2048;  }
  else if (t < 10240) { src=W2;  stride=SD;  rowoff=0;   NT=8;  dst=ws+OFF_W2/2;   local=t-8192;  }
  else if (t < 12288) { src=W3;  stride=SD;  rowoff=0;   NT=8;  dst=ws+OFF_W3/2;   local=t-10240; }
  else if (t < 20480) { src=Win; stride=512; rowoff=0;   NT=32; dst=ws+OFF_WIN/2;  local=t-12288; }
  else                { src=Wout;stride=SD;  rowoff=0;   NT=8;  dst=ws+OFF_WOUT/2; local=t-20480; }
  int lane = local & 63;
  int blk  = local >> 6;
  int nt = blk % NT, ks = blk / NT;
  int k0 = rowoff + ks*32 + (lane>>4)*8;
  int n  = nt*16 + (lane & 15);
  union { u16 a[8]; short8 v; } tmp;
  #pragma unroll
  for (int j=0;j<8;j++) tmp.a[j] = f2b(src[(size_t)(k0+j)*stride + n]);
  *reinterpret_cast<short8*>(dst + (size_t)local*8) = tmp.v;
}

// shared inner loop for G2/G3: 48x128 @ 128x128, A from LDS, B from L2 with 1-ks lookahead
__device__ __forceinline__ void mlp128(const u16* __restrict__ Bb, const u16* HHw,
                                       int l16, int quad, f32x4 acc[24])
{
  short8 bc[8], bn[8];
  #pragma unroll
  for (int nt=0;nt<8;nt++) bc[nt] = ldg8(Bb + ((size_t)nt*64)*8);
  #pragma unroll
  for (int ks=0; ks<4; ks++){
    if (ks < 3){
      #pragma unroll
      for (int nt=0;nt<8;nt++) bn[nt] = ldg8(Bb + ((size_t)((ks+1)*8+nt)*64)*8);
    }
    short8 af[3];
    #pragma unroll
    for (int mt=0; mt<3; mt++)
      af[mt] = *reinterpret_cast<const short8*>(&HHw[(size_t)(mt*16+l16)*HPAD + ks*32 + quad*8]);
    #pragma unroll
    for (int nt=0; nt<8; nt++)
      #pragma unroll
      for (int mt=0; mt<3; mt++)
        acc[mt*8+nt] = __builtin_amdgcn_mfma_f32_16x16x32_bf16(af[mt], bc[nt], acc[mt*8+nt], 0,0,0);
    if (ks < 3){
      #pragma unroll
      for (int nt=0;nt<8;nt++) bc[nt] = bn[nt];
    }
  }
}

// G1 helpers: depth-2 rotating register prefetch of h_E
#define LDA(BUF, kk) { _Pragma("unroll") for (int mt=0; mt<3; mt++){ \
    BUF[mt][0] = *reinterpret_cast<const float4*>(Ab + (size_t)mt*16*SNIN + (kk)*32); \
    BUF[mt][1] = *reinterpret_cast<const float4*>(Ab + (size_t)mt*16*SNIN + (kk)*32 + 4); } }

#define G1STEP(CUR, NXT, ks, PF) { \
    if (PF) LDA(NXT, (ks)+2); \
    short8 af[3]; \
    _Pragma("unroll") for (int mt=0; mt<3; mt++) af[mt] = pack8(CUR[mt][0], CUR[mt][1]); \
    _Pragma("unroll") for (int nt=0; nt<8; nt++){ \
      short8 bf = ldg8(Bb + ((size_t)((ks)*8+nt)*64)*8); \
      _Pragma("unroll") for (int mt=0; mt<3; mt++) \
        acc[mt*8+nt] = __builtin_amdgcn_mfma_f32_16x16x32_bf16(af[mt], bf, acc[mt*8+nt], 0,0,0); \
    } }

#define B1STEP(HB, ks) { \
    short8 af = pack8(HB[0], HB[1]); \
    _Pragma("unroll") for (int nt=0; nt<8; nt++){ \
      short8 bf = ldg8(Bb1 + ((size_t)((ks)*8+nt)*64)*8); \
      accb[nt] = __builtin_amdgcn_mfma_f32_16x16x32_bf16(af, bf, accb[nt], 0,0,0); \
    } }

// ---------------- kernel A: one wave per node; fused MLP + masked K-sum + LN1 ----------------
__global__ __launch_bounds__(256, 2) void dec_nodes(
    const float* __restrict__ hV, const float* __restrict__ hE, const float* __restrict__ mAtt,
    const float* __restrict__ b1, const float* __restrict__ b2, const float* __restrict__ b3,
    const float* __restrict__ g1, const float* __restrict__ o1,
    const u16* __restrict__ ws, float* __restrict__ u_out)
{
  __shared__ u16 HH[4][SK*HPAD];   // per-wave scratch: holds H1, then reused for H2

  const int tid  = threadIdx.x;
  const int w    = tid >> 6;
  const int lane = tid & 63;
  const int quad = lane >> 4;
  const int l16  = lane & 15;
  const int g    = blockIdx.x*4 + w;   // this wave's node
  u16* HHw = HH[w];

  // ---- base1[n] = (hV[g] @ W1[:128])[n] + b1[n]; all 4 ks hoisted upfront
  float base1v[8];
  {
    f32x4 accb[8];
    #pragma unroll
    for (int nt=0;nt<8;nt++) accb[nt] = (f32x4){0.f,0.f,0.f,0.f};
    const u16* Bb1 = ws + OFF_W1A/2 + (size_t)lane*8;
    const float* hp = hV + (size_t)g*SD + quad*8;
    float4 H0[2], H1[2], H2[2], H3[2];
    H0[0] = *reinterpret_cast<const float4*>(hp);       H0[1] = *reinterpret_cast<const float4*>(hp+4);
    H1[0] = *reinterpret_cast<const float4*>(hp+32);    H1[1] = *reinterpret_cast<const float4*>(hp+36);
    H2[0] = *reinterpret_cast<const float4*>(hp+64);    H2[1] = *reinterpret_cast<const float4*>(hp+68);
    H3[0] = *reinterpret_cast<const float4*>(hp+96);    H3[1] = *reinterpret_cast<const float4*>(hp+100);
    B1STEP(H0,0); B1STEP(H1,1); B1STEP(H2,2); B1STEP(H3,3);
    #pragma unroll
    for (int nt=0;nt<8;nt++) base1v[nt] = accb[nt][0] + b1[nt*16 + l16];
  }

  // ---- G1: H1 = gelu(hE[g] (48x384) @ W1[128:] + base1), h_E prefetched 2 ks ahead
  f32x4 acc[24];
  #pragma unroll
  for (int i=0;i<24;i++) acc[i] = (f32x4){0.f,0.f,0.f,0.f};
  {
    const float* Ab = hE + (size_t)g*(SK*SNIN) + (size_t)l16*SNIN + quad*8;
    const u16*  Bb = ws + OFF_W1B/2 + (size_t)lane*8;
    float4 A0[3][2], A1[3][2], A2[3][2];
    LDA(A0,0); LDA(A1,1);
    G1STEP(A0,A2,0,1);  G1STEP(A1,A0,1,1);  G1STEP(A2,A1,2,1);
    G1STEP(A0,A2,3,1);  G1STEP(A1,A0,4,1);  G1STEP(A2,A1,5,1);
    G1STEP(A0,A2,6,1);  G1STEP(A1,A0,7,1);  G1STEP(A2,A1,8,1);
    G1STEP(A0,A2,9,1);  G1STEP(A1,A0,10,0); G1STEP(A2,A1,11,0);
    #pragma unroll
    for (int mt=0; mt<3; mt++)
      #pragma unroll
      for (int nt=0; nt<8; nt++)
        #pragma unroll
        for (int i=0;i<4;i++){
          int row = mt*16 + quad*4 + i;
          HHw[row*HPAD + nt*16 + l16] = f2b(gelu_f(acc[mt*8+nt][i] + base1v[nt]));
        }
  }
  __syncthreads();

  // ---- G2: H2 = gelu(H1 @ W2 + b2)
  #pragma unroll
  for (int i=0;i<24;i++) acc[i] = (f32x4){0.f,0.f,0.f,0.f};
  mlp128(ws + OFF_W2/2 + (size_t)lane*8, HHw, l16, quad, acc);
  __syncthreads();   // all H1 reads done before overwrite (also compiler fence)
  {
    #pragma unroll
    for (int mt=0; mt<3; mt++)
      #pragma unroll
      for (int nt=0; nt<8; nt++){
        float bb = b2[nt*16 + l16];
        #pragma unroll
        for (int i=0;i<4;i++){
          int row = mt*16 + quad*4 + i;
          HHw[row*HPAD + nt*16 + l16] = f2b(gelu_f(acc[mt*8+nt][i] + bb));
        }
      }
  }
  __syncthreads();

  // ---- G3: M = H2 @ W3 + b3; dh[n] = sum_k mask[k]*M[k][n]
  #pragma unroll
  for (int i=0;i<24;i++) acc[i] = (f32x4){0.f,0.f,0.f,0.f};
  mlp128(ws + OFF_W3/2 + (size_t)lane*8, HHw, l16, quad, acc);
  float p[8];
  {
    #pragma unroll
    for (int nt=0;nt<8;nt++) p[nt] = 0.f;
    #pragma unroll
    for (int mt=0; mt<3; mt++)
      #pragma unroll
      for (int i=0;i<4;i++){
        float m = mAtt[(size_t)g*SK + mt*16 + quad*4 + i];
        #pragma unroll
        for (int nt=0; nt<8; nt++){
          float bb = b3[nt*16 + l16];
          p[nt] = fmaf(m, acc[mt*8+nt][i] + bb, p[nt]);
        }
      }
    #pragma unroll
    for (int nt=0;nt<8;nt++){
      p[nt] += __shfl_down(p[nt], 32, 64);
      p[nt] += __shfl_down(p[nt], 16, 64);
      p[nt]  = __shfl(p[nt], l16, 64);     // broadcast quad0's reduced value to all quads
    }
  }

  // ---- LN1: u = LN(hV + dh/30)*g1 + o1   (each col counted 4x across quads in the wave sum)
  {
    float x[8];
    float s = 0.f, q = 0.f;
    #pragma unroll
    for (int nt=0;nt<8;nt++){
      x[nt] = hV[(size_t)g*SD + nt*16 + l16] + p[nt]*(1.0f/30.0f);
      s += x[nt]; q = fmaf(x[nt], x[nt], q);
    }
    #pragma unroll
    for (int off=1; off<64; off<<=1){ s += __shfl_xor(s, off, 64); q += __shfl_xor(q, off, 64); }
    float mu  = s * (1.0f/512.0f);          // 4x duplication: /(4*128)
    float var = q * (1.0f/512.0f) - mu*mu;
    float rs  = rsqrtf(var + 1e-5f);
    #pragma unroll
    for (int k=0;k<2;k++){
      int nt = 2*quad + k;
      float uv = (x[nt]-mu)*rs*g1[nt*16+l16] + o1[nt*16+l16];
      u_out[(size_t)g*SD + nt*16 + l16] = uv;
    }
  }
}

// ---------------- kernel B: batched FFN + residual + LN2 + mask_V (in-place on d_out) --------
// 512 blocks x 256 thr (4 waves), 16 rows/block; FFN1 split by N (wave w: cols w*128..),
// FFN2 split by N (wave w: col tiles 2w,2w+1), LN2 via fp32 LDS exchange. 4x the wave
// parallelism of the previous 256x128 layout (was 0.5 waves/SIMD, pure latency-bound).
__global__ __launch_bounds__(256) void ffn_ln(
    const float* __restrict__ b_in, const float* __restrict__ b_out,
    const float* __restrict__ g2, const float* __restrict__ o2, const float* __restrict__ mV,
    const u16* __restrict__ ws, float* __restrict__ uo)
{
  __shared__ u16 fS[16*FPAD];
  __shared__ float dS[16][132];
  const int tid = threadIdx.x, w = tid>>6, lane = tid&63, quad = lane>>4, l16 = lane&15;
  const int m0 = blockIdx.x*16;

  // A-frags for rows m0..m0+15 (same for all 4 waves)
  short8 afr[4];
  const float* Ap = uo + (size_t)(m0 + l16)*SD + quad*8;
  #pragma unroll
  for (int ks=0; ks<4; ks++) afr[ks] = cvt8(Ap + ks*32);

  // FFN1: wave w computes f cols [w*128, w*128+128)
  {
    f32x4 acc[8];
    #pragma unroll
    for (int t=0;t<8;t++) acc[t] = (f32x4){0.f,0.f,0.f,0.f};
    const u16* Bp = ws + OFF_WIN/2 + ((size_t)(w*8)*64 + lane)*8;
    #pragma unroll
    for (int ks=0; ks<4; ks++){
      #pragma unroll
      for (int t=0;t<8;t++){
        short8 bf = ldg8(Bp + ((size_t)ks*32 + t)*512);
        acc[t] = __builtin_amdgcn_mfma_f32_16x16x32_bf16(afr[ks], bf, acc[t], 0,0,0);
      }
    }
    #pragma unroll
    for (int t=0;t<8;t++){
      int coln = w*128 + t*16 + l16;
      float bi = b_in[coln];
      #pragma unroll
      for (int i=0;i<4;i++)
        fS[(quad*4+i)*FPAD + coln] = f2b(gelu_f(acc[t][i] + bi));
    }
  }
  __syncthreads();

  // FFN2: wave w computes dh2 col tiles 2w, 2w+1 over full K=512
  {
    f32x4 acc2[2];
    acc2[0] = (f32x4){0.f,0.f,0.f,0.f};
    acc2[1] = (f32x4){0.f,0.f,0.f,0.f};
    const u16* Bo = ws + OFF_WOUT/2 + (size_t)lane*8;
    #pragma unroll
    for (int ks=0; ks<16; ks++){
      const short8 af = *reinterpret_cast<const short8*>(&fS[l16*FPAD + ks*32 + quad*8]);
      #pragma unroll
      for (int j=0;j<2;j++){
        short8 bf = ldg8(Bo + ((size_t)ks*8 + (w*2+j))*512);
        acc2[j] = __builtin_amdgcn_mfma_f32_16x16x32_bf16(af, bf, acc2[j], 0,0,0);
      }
    }
    #pragma unroll
    for (int j=0;j<2;j++){
      int cl = (w*2+j)*16 + l16;
      float bo = b_out[cl];
      #pragma unroll
      for (int i=0;i<4;i++)
        dS[quad*4+i][cl] = acc2[j][i] + bo;
    }
  }
  __syncthreads();

  // residual + LN2 + mask_V for row r = m0 + w*4 + quad
  {
    int rl = w*4 + quad;
    int r  = m0 + rl;
    float xv[8]; float s = 0.f, q = 0.f;
    #pragma unroll
    for (int t=0;t<8;t++){
      xv[t] = uo[(size_t)r*SD + t*16 + l16] + dS[rl][t*16 + l16];
      s += xv[t]; q = fmaf(xv[t], xv[t], q);
    }
    #pragma unroll
    for (int mk=1; mk<16; mk<<=1){ s += __shfl_xor(s, mk, 64); q += __shfl_xor(q, mk, 64); }
    float mu  = s * (1.0f/128.0f);
    float var = q * (1.0f/128.0f) - mu*mu;
    float rs  = rsqrtf(var + 1e-5f);
    float mv  = mV[r];
    #pragma unroll
    for (int t=0;t<8;t++){
      int cl = t*16 + l16;
      uo[(size_t)r*SD + cl] = mv * ((xv[t]-mu)*rs*g2[cl] + o2[cl]);
    }
  }
}

extern "C" void kernel_launch(void* const* d_in, const int* in_sizes, int n_in,
                              void* d_out, int out_size, void* d_ws, size_t ws_size,
                              hipStream_t stream) {
  (void)n_in; (void)out_size; (void)ws_size;
  const float* hV    = (const float*)d_in[0];
  const float* hE    = (const float*)d_in[1];
  const float* mV    = (const float*)d_in[2];
  const float* mAtt  = (const float*)d_in[3];
  const float* W1    = (const float*)d_in[4];
  const float* b1    = (const float*)d_in[5];
  const float* W2    = (const float*)d_in[6];
  const float* b2    = (const float*)d_in[7];
  const float* W3    = (const float*)d_in[8];
  const float* b3    = (const float*)d_in[9];
  const float* Win   = (const float*)d_in[10];
  const float* b_in  = (const float*)d_in[11];
  const float* Wout  = (const float*)d_in[12];
  const float* b_out = (const float*)d_in[13];
  const float* g1    = (const float*)d_in[14];
  const float* o1    = (const float*)d_in[15];
  const float* g2    = (const float*)d_in[16];
  const float* o2    = (const float*)d_in[17];
  u16*   ws   = (u16*)d_ws;
  float* outp = (float*)d_out;
  const int NG = in_sizes[0] / SD;   // 8192 nodes

  hipLaunchKernelGGL(prep_pack, dim3(112), dim3(256), 0, stream, W1, W2, W3, Win, Wout, ws);
  hipLaunchKernelGGL(dec_nodes, dim3(NG/4), dim3(256), 0, stream,
                     hV, hE, mAtt, b1, b2, b3, g1, o1, ws, outp);
  hipLaunchKernelGGL(ffn_ln, dim3(NG/16), dim3(256), 0, stream,
                     b_in, b_out, g2, o2, mV, ws, outp);
}

// Round 2
// 862.527 us; speedup vs baseline: 1.1656x; 1.0486x over previous
//
#include <hip/hip_runtime.h>
#include <hip/hip_bf16.h>

typedef unsigned short u16;
typedef __attribute__((ext_vector_type(8))) short short8;
typedef __attribute__((ext_vector_type(4))) float f32x4;

#define SD   128
#define SNIN 384
#define SK   48
#define FPAD 520   // 512+8 elems (ffn_ln LDS row stride)

// ws layout (bytes) — packed bf16 weights only (448 KB total)
#define OFF_W1A   0
#define OFF_W1B   32768
#define OFF_W2    131072
#define OFF_W3    163840
#define OFF_WIN   196608
#define OFF_WOUT  327680

__device__ __forceinline__ u16 f2b(float f){
  union { float f; unsigned u; } v; v.f = f;
  unsigned r = (v.u + 0x7FFFu + ((v.u >> 16) & 1u)) >> 16;   // RNE
  return (u16)r;
}
__device__ __forceinline__ short8 ldg8(const u16* p){
  return *reinterpret_cast<const short8*>(p);
}
// pack 8 fp32 (two float4) -> bf16x8 via v_cvt_pk_bf16_f32 (RNE, 4 instrs)
__device__ __forceinline__ short8 pack8(float4 a, float4 b){
  union { unsigned u[4]; short8 s; } r;
  asm("v_cvt_pk_bf16_f32 %0, %1, %2" : "=v"(r.u[0]) : "v"(a.x), "v"(a.y));
  asm("v_cvt_pk_bf16_f32 %0, %1, %2" : "=v"(r.u[1]) : "v"(a.z), "v"(a.w));
  asm("v_cvt_pk_bf16_f32 %0, %1, %2" : "=v"(r.u[2]) : "v"(b.x), "v"(b.y));
  asm("v_cvt_pk_bf16_f32 %0, %1, %2" : "=v"(r.u[3]) : "v"(b.z), "v"(b.w));
  return r.s;
}
__device__ __forceinline__ short8 cvt8(const float* p){
  float4 a = *reinterpret_cast<const float4*>(p);
  float4 b = *reinterpret_cast<const float4*>(p + 4);
  return pack8(a, b);
}
// async global->LDS, 16B per lane; lds base must be wave-uniform (HW adds lane*16)
__device__ __forceinline__ void gl_lds16(const float* g, float* l){
  __builtin_amdgcn_global_load_lds((const __attribute__((address_space(1))) void*)g,
                                   (__attribute__((address_space(3))) void*)l, 16, 0, 0);
}

// gelu(x)=0.5*x*(1+erf(x/sqrt2)); odd deg-7 poly of erf on [-3,3], clamped. abs err < 7e-3.
__device__ __forceinline__ float gelu_f(float x){
  float xc = fminf(3.0f, fmaxf(-3.0f, x));
  float u  = xc*xc;
  float p  = fmaf(u, fmaf(u, fmaf(u, -4.81034e-4f, 1.185750e-2f), -1.1877797e-1f), 7.9165011e-1f);
  float t  = xc*p;
  float hx = 0.5f*x;
  return fmaf(t, hx, hx);
}

// ---------------- prep: fp32 weights -> bf16 MFMA B-fragment-linear layout ----------------
// B-frag (16x16x32): lane holds B[k=(lane>>4)*8+j][n=nt*16+(lane&15)], j=0..7.
// Frag order: ((ks*NT + nt)*64 + lane)*8 elems -> 16B contiguous per lane.
__global__ __launch_bounds__(256) void prep_pack(
    const float* __restrict__ W1, const float* __restrict__ W2, const float* __restrict__ W3,
    const float* __restrict__ Win, const float* __restrict__ Wout, u16* __restrict__ ws)
{
  int t = blockIdx.x*256 + threadIdx.x;   // 28672 frag-lanes total
  const float* src; int stride, rowoff, NT; u16* dst; int local;
  if (t < 2048)       { src=W1;  stride=SD;  rowoff=0;   NT=8;  dst=ws+OFF_W1A/2;  local=t;       }
  else if (t < 8192)  { src=W1;  stride=SD;  rowoff=128; NT=8;  dst=ws+OFF_W1B/2;  local=t-2048;  }
  else if (t < 10240) { src=W2;  stride=SD;  rowoff=0;   NT=8;  dst=ws+OFF_W2/2;   local=t-8192;  }
  else if (t < 12288) { src=W3;  stride=SD;  rowoff=0;   NT=8;  dst=ws+OFF_W3/2;   local=t-10240; }
  else if (t < 20480) { src=Win; stride=512; rowoff=0;   NT=32; dst=ws+OFF_WIN/2;  local=t-12288; }
  else                { src=Wout;stride=SD;  rowoff=0;   NT=8;  dst=ws+OFF_WOUT/2; local=t-20480; }
  int lane = local & 63;
  int blk  = local >> 6;
  int nt = blk % NT, ks = blk / NT;
  int k0 = rowoff + ks*32 + (lane>>4)*8;
  int n  = nt*16 + (lane & 15);
  union { u16 a[8]; short8 v; } tmp;
  #pragma unroll
  for (int j=0;j<8;j++) tmp.a[j] = f2b(src[(size_t)(k0+j)*stride + n]);
  *reinterpret_cast<short8*>(dst + (size_t)local*8) = tmp.v;
}

// ---------------- kernel A: one BLOCK per node (4 waves cooperate) ----------------
// G1: hE (48x384, HBM) staged to LDS via global_load_lds (double-buffered, 6KB/ks,
// XOR slot-swizzle with pre-swizzled source); weights (L2) prefetched 1 step ahead
// so the barrier drain covers them for free. N=128 split as 2 nt-tiles per wave.
// H1/H2 in a swizzled 12KB LDS buffer (conflict-free b128 reads in G2/G3).
__global__ __launch_bounds__(256, 4) void dec_nodes(
    const float* __restrict__ hV, const float* __restrict__ hE, const float* __restrict__ mAtt,
    const float* __restrict__ b1, const float* __restrict__ b2, const float* __restrict__ b3,
    const float* __restrict__ g1, const float* __restrict__ o1,
    const u16* __restrict__ ws, float* __restrict__ u_out)
{
  __shared__ __align__(16) float STG[2][1536];   // 2 x 6KB fp32 hE staging (swizzled slots)
  __shared__ __align__(16) u16   HHs[48*128];    // 12KB H buffer, row stride 256B, swizzled
  __shared__ float LNS[8];

  const int tid  = threadIdx.x;
  const int w    = tid >> 6;
  const int lane = tid & 63;
  const int quad = lane >> 4;
  const int l16  = lane & 15;
  const int g    = blockIdx.x;     // this block's node
  const int n0   = w*2;            // this wave's first nt tile (cols n0*16 .. n0*16+31)

  // per-lane staging source: row=(lane>>3), phys slot=(lane&7) holds logical slot (lane&7)^(row&7)
  const float* gsrcl = hE + (size_t)g*(SK*SNIN) + (size_t)(lane>>3)*SNIN
                          + (size_t)(((lane&7) ^ (lane>>3))*4);

  // stage instr j covers rows j*8..j*8+7 (1KB). waves 0,1 issue 2; waves 2,3 issue 1.
  #define STAGE(ks, buf) { \
    if (w < 2){ gl_lds16(gsrcl + (size_t)(2*w)*8*SNIN   + (ks)*32, &STG[buf][(2*w)*256]);   \
                gl_lds16(gsrcl + (size_t)(2*w+1)*8*SNIN + (ks)*32, &STG[buf][(2*w+1)*256]); } \
    else      { gl_lds16(gsrcl + (size_t)(w+2)*8*SNIN   + (ks)*32, &STG[buf][(w+2)*256]);   } }

  STAGE(0, 0);   // get HBM going first

  // ---- base1[j] = (hV[g] @ W1[:128])[col] + b1[col], col=(n0+j)*16+l16, broadcast-A MFMA
  float base1v[2];
  {
    f32x4 accb[2] = {(f32x4){0.f,0.f,0.f,0.f},(f32x4){0.f,0.f,0.f,0.f}};
    const float* hp = hV + (size_t)g*SD + quad*8;
    const u16* Bb1 = ws + OFF_W1A/2 + (size_t)lane*8;
    #pragma unroll
    for (int ks=0; ks<4; ks++){
      short8 af = cvt8(hp + ks*32);
      #pragma unroll
      for (int j=0;j<2;j++){
        short8 bf = ldg8(Bb1 + ((size_t)(ks*8 + n0 + j)*64)*8);
        accb[j] = __builtin_amdgcn_mfma_f32_16x16x32_bf16(af, bf, accb[j], 0,0,0);
      }
    }
    #pragma unroll
    for (int j=0;j<2;j++) base1v[j] = accb[j][0] + b1[(n0+j)*16 + l16];
  }

  // ---- G1: H1 = gelu(hE @ W1[128:] + base1)
  const u16* BbG1 = ws + OFF_W1B/2 + (size_t)lane*8;
  short8 bq0 = ldg8(BbG1 + ((size_t)(n0)*64)*8);
  short8 bq1 = ldg8(BbG1 + ((size_t)(n0+1)*64)*8);
  __syncthreads();   // stage(0) + base1 loads + B(0) all complete

  f32x4 acc[3][2];
  #pragma unroll
  for (int mt=0;mt<3;mt++){ acc[mt][0]=(f32x4){0.f,0.f,0.f,0.f}; acc[mt][1]=(f32x4){0.f,0.f,0.f,0.f}; }

  #pragma unroll
  for (int ks=0; ks<12; ks++){
    short8 bn0, bn1;
    if (ks < 11){
      bn0 = ldg8(BbG1 + ((size_t)((ks+1)*8 + n0)*64)*8);     // B before stage: older in vm queue
      bn1 = ldg8(BbG1 + ((size_t)((ks+1)*8 + n0+1)*64)*8);
      STAGE(ks+1, (ks+1)&1);
    }
    const float* bufF = STG[ks&1];
    short8 af[3];
    #pragma unroll
    for (int mt=0;mt<3;mt++){
      int row = mt*16 + l16;
      int sp0 = (2*quad) ^ (l16 & 7);
      float4 a = *reinterpret_cast<const float4*>(bufF + row*32 + sp0*4);
      float4 b = *reinterpret_cast<const float4*>(bufF + row*32 + (sp0^1)*4);
      af[mt] = pack8(a, b);
    }
    #pragma unroll
    for (int mt=0;mt<3;mt++){
      acc[mt][0] = __builtin_amdgcn_mfma_f32_16x16x32_bf16(af[mt], bq0, acc[mt][0], 0,0,0);
      acc[mt][1] = __builtin_amdgcn_mfma_f32_16x16x32_bf16(af[mt], bq1, acc[mt][1], 0,0,0);
    }
    __syncthreads();   // drain: stage(ks+1)+B(ks+1) complete; buf[ks&1] free to overwrite
    if (ks < 11){ bq0 = bn0; bq1 = bn1; }
  }

  // H1 -> HHs (swizzled: phys slot = (col>>3) ^ (row&15))
  #pragma unroll
  for (int mt=0; mt<3; mt++)
    #pragma unroll
    for (int j=0; j<2; j++)
      #pragma unroll
      for (int i=0;i<4;i++){
        int row = mt*16 + quad*4 + i;
        int col = (n0+j)*16 + l16;
        HHs[row*128 + (((col>>3) ^ (row&15))<<3) + (col&7)] = f2b(gelu_f(acc[mt][j][i] + base1v[j]));
      }
  __syncthreads();

  // ---- G2: H2 = gelu(H1 @ W2 + b2)
  #pragma unroll
  for (int mt=0;mt<3;mt++){ acc[mt][0]=(f32x4){0.f,0.f,0.f,0.f}; acc[mt][1]=(f32x4){0.f,0.f,0.f,0.f}; }
  {
    const u16* Bb = ws + OFF_W2/2 + (size_t)lane*8;
    #pragma unroll
    for (int ks=0; ks<4; ks++){
      short8 afm[3];
      #pragma unroll
      for (int mt=0; mt<3; mt++){
        int row = mt*16 + l16;
        int sp  = (ks*4 + quad) ^ l16;
        afm[mt] = *reinterpret_cast<const short8*>(HHs + row*128 + sp*8);
      }
      #pragma unroll
      for (int j=0;j<2;j++){
        short8 bf = ldg8(Bb + ((size_t)(ks*8 + n0 + j)*64)*8);
        #pragma unroll
        for (int mt=0;mt<3;mt++)
          acc[mt][j] = __builtin_amdgcn_mfma_f32_16x16x32_bf16(afm[mt], bf, acc[mt][j], 0,0,0);
      }
    }
  }
  __syncthreads();   // all H1 reads done before overwrite
  #pragma unroll
  for (int mt=0; mt<3; mt++)
    #pragma unroll
    for (int j=0; j<2; j++){
      float bb = b2[(n0+j)*16 + l16];
      #pragma unroll
      for (int i=0;i<4;i++){
        int row = mt*16 + quad*4 + i;
        int col = (n0+j)*16 + l16;
        HHs[row*128 + (((col>>3) ^ (row&15))<<3) + (col&7)] = f2b(gelu_f(acc[mt][j][i] + bb));
      }
    }
  __syncthreads();

  // ---- G3: M = H2 @ W3 + b3; dh[col] = sum_k mask[k]*M[k][col]
  #pragma unroll
  for (int mt=0;mt<3;mt++){ acc[mt][0]=(f32x4){0.f,0.f,0.f,0.f}; acc[mt][1]=(f32x4){0.f,0.f,0.f,0.f}; }
  {
    const u16* Bb = ws + OFF_W3/2 + (size_t)lane*8;
    #pragma unroll
    for (int ks=0; ks<4; ks++){
      short8 afm[3];
      #pragma unroll
      for (int mt=0; mt<3; mt++){
        int row = mt*16 + l16;
        int sp  = (ks*4 + quad) ^ l16;
        afm[mt] = *reinterpret_cast<const short8*>(HHs + row*128 + sp*8);
      }
      #pragma unroll
      for (int j=0;j<2;j++){
        short8 bf = ldg8(Bb + ((size_t)(ks*8 + n0 + j)*64)*8);
        #pragma unroll
        for (int mt=0;mt<3;mt++)
          acc[mt][j] = __builtin_amdgcn_mfma_f32_16x16x32_bf16(afm[mt], bf, acc[mt][j], 0,0,0);
      }
    }
  }
  float p0 = 0.f, p1 = 0.f;
  {
    float b3v0 = b3[(n0)*16 + l16], b3v1 = b3[(n0+1)*16 + l16];
    #pragma unroll
    for (int mt=0; mt<3; mt++)
      #pragma unroll
      for (int i=0;i<4;i++){
        float m = mAtt[(size_t)g*SK + mt*16 + quad*4 + i];
        p0 = fmaf(m, acc[mt][0][i] + b3v0, p0);
        p1 = fmaf(m, acc[mt][1][i] + b3v1, p1);
      }
    p0 += __shfl_down(p0, 32, 64); p0 += __shfl_down(p0, 16, 64); p0 = __shfl(p0, l16, 64);
    p1 += __shfl_down(p1, 32, 64); p1 += __shfl_down(p1, 16, 64); p1 = __shfl(p1, l16, 64);
  }

  // ---- LN1 (cross-wave via LDS; each col counted 4x across quads -> /512)
  {
    float x0 = hV[(size_t)g*SD + (n0)*16   + l16] + p0*(1.0f/30.0f);
    float x1 = hV[(size_t)g*SD + (n0+1)*16 + l16] + p1*(1.0f/30.0f);
    float s = x0 + x1;
    float q = fmaf(x0, x0, x1*x1);
    #pragma unroll
    for (int off=1; off<64; off<<=1){ s += __shfl_xor(s, off, 64); q += __shfl_xor(q, off, 64); }
    if (lane == 0){ LNS[w] = s; LNS[4+w] = q; }
    __syncthreads();
    s = LNS[0]+LNS[1]+LNS[2]+LNS[3];
    q = LNS[4]+LNS[5]+LNS[6]+LNS[7];
    float mu  = s * (1.0f/512.0f);
    float var = q * (1.0f/512.0f) - mu*mu;
    float rs  = rsqrtf(var + 1e-5f);
    if (quad == 0){
      int c0 = (n0)*16 + l16, c1 = (n0+1)*16 + l16;
      u_out[(size_t)g*SD + c0] = (x0-mu)*rs*g1[c0] + o1[c0];
      u_out[(size_t)g*SD + c1] = (x1-mu)*rs*g1[c1] + o1[c1];
    }
  }
  #undef STAGE
}

// ---------------- kernel B: batched FFN + residual + LN2 + mask_V (in-place on d_out) --------
// 512 blocks x 256 thr (4 waves), 16 rows/block; FFN1 split by N (wave w: cols w*128..),
// FFN2 split by N (wave w: col tiles 2w,2w+1), LN2 via fp32 LDS exchange.
__global__ __launch_bounds__(256) void ffn_ln(
    const float* __restrict__ b_in, const float* __restrict__ b_out,
    const float* __restrict__ g2, const float* __restrict__ o2, const float* __restrict__ mV,
    const u16* __restrict__ ws, float* __restrict__ uo)
{
  __shared__ u16 fS[16*FPAD];
  __shared__ float dS[16][132];
  const int tid = threadIdx.x, w = tid>>6, lane = tid&63, quad = lane>>4, l16 = lane&15;
  const int m0 = blockIdx.x*16;

  // A-frags for rows m0..m0+15 (same for all 4 waves)
  short8 afr[4];
  const float* Ap = uo + (size_t)(m0 + l16)*SD + quad*8;
  #pragma unroll
  for (int ks=0; ks<4; ks++) afr[ks] = cvt8(Ap + ks*32);

  // FFN1: wave w computes f cols [w*128, w*128+128)
  {
    f32x4 acc[8];
    #pragma unroll
    for (int t=0;t<8;t++) acc[t] = (f32x4){0.f,0.f,0.f,0.f};
    const u16* Bp = ws + OFF_WIN/2 + ((size_t)(w*8)*64 + lane)*8;
    #pragma unroll
    for (int ks=0; ks<4; ks++){
      #pragma unroll
      for (int t=0;t<8;t++){
        short8 bf = ldg8(Bp + ((size_t)ks*32 + t)*512);
        acc[t] = __builtin_amdgcn_mfma_f32_16x16x32_bf16(afr[ks], bf, acc[t], 0,0,0);
      }
    }
    #pragma unroll
    for (int t=0;t<8;t++){
      int coln = w*128 + t*16 + l16;
      float bi = b_in[coln];
      #pragma unroll
      for (int i=0;i<4;i++)
        fS[(quad*4+i)*FPAD + coln] = f2b(gelu_f(acc[t][i] + bi));
    }
  }
  __syncthreads();

  // FFN2: wave w computes dh2 col tiles 2w, 2w+1 over full K=512
  {
    f32x4 acc2[2];
    acc2[0] = (f32x4){0.f,0.f,0.f,0.f};
    acc2[1] = (f32x4){0.f,0.f,0.f,0.f};
    const u16* Bo = ws + OFF_WOUT/2 + (size_t)lane*8;
    #pragma unroll
    for (int ks=0; ks<16; ks++){
      const short8 af = *reinterpret_cast<const short8*>(&fS[l16*FPAD + ks*32 + quad*8]);
      #pragma unroll
      for (int j=0;j<2;j++){
        short8 bf = ldg8(Bo + ((size_t)ks*8 + (w*2+j))*512);
        acc2[j] = __builtin_amdgcn_mfma_f32_16x16x32_bf16(af, bf, acc2[j], 0,0,0);
      }
    }
    #pragma unroll
    for (int j=0;j<2;j++){
      int cl = (w*2+j)*16 + l16;
      float bo = b_out[cl];
      #pragma unroll
      for (int i=0;i<4;i++)
        dS[quad*4+i][cl] = acc2[j][i] + bo;
    }
  }
  __syncthreads();

  // residual + LN2 + mask_V for row r = m0 + w*4 + quad
  {
    int rl = w*4 + quad;
    int r  = m0 + rl;
    float xv[8]; float s = 0.f, q = 0.f;
    #pragma unroll
    for (int t=0;t<8;t++){
      xv[t] = uo[(size_t)r*SD + t*16 + l16] + dS[rl][t*16 + l16];
      s += xv[t]; q = fmaf(xv[t], xv[t], q);
    }
    #pragma unroll
    for (int mk=1; mk<16; mk<<=1){ s += __shfl_xor(s, mk, 64); q += __shfl_xor(q, mk, 64); }
    float mu  = s * (1.0f/128.0f);
    float var = q * (1.0f/128.0f) - mu*mu;
    float rs  = rsqrtf(var + 1e-5f);
    float mv  = mV[r];
    #pragma unroll
    for (int t=0;t<8;t++){
      int cl = t*16 + l16;
      uo[(size_t)r*SD + cl] = mv * ((xv[t]-mu)*rs*g2[cl] + o2[cl]);
    }
  }
}

extern "C" void kernel_launch(void* const* d_in, const int* in_sizes, int n_in,
                              void* d_out, int out_size, void* d_ws, size_t ws_size,
                              hipStream_t stream) {
  (void)n_in; (void)out_size; (void)ws_size;
  const float* hV    = (const float*)d_in[0];
  const float* hE    = (const float*)d_in[1];
  const float* mV    = (const float*)d_in[2];
  const float* mAtt  = (const float*)d_in[3];
  const float* W1    = (const float*)d_in[4];
  const float* b1    = (const float*)d_in[5];
  const float* W2    = (const float*)d_in[6];
  const float* b2    = (const float*)d_in[7];
  const float* W3    = (const float*)d_in[8];
  const float* b3    = (const float*)d_in[9];
  const float* Win   = (const float*)d_in[10];
  const float* b_in  = (const float*)d_in[11];
  const float* Wout  = (const float*)d_in[12];
  const float* b_out = (const float*)d_in[13];
  const float* g1    = (const float*)d_in[14];
  const float* o1    = (const float*)d_in[15];
  const float* g2    = (const float*)d_in[16];
  const float* o2    = (const float*)d_in[17];
  u16*   ws   = (u16*)d_ws;
  float* outp = (float*)d_out;
  const int NG = in_sizes[0] / SD;   // 8192 nodes

  hipLaunchKernelGGL(prep_pack, dim3(112), dim3(256), 0, stream, W1, W2, W3, Win, Wout, ws);
  hipLaunchKernelGGL(dec_nodes, dim3(NG), dim3(256), 0, stream,
                     hV, hE, mAtt, b1, b2, b3, g1, o1, ws, outp);
  hipLaunchKernelGGL(ffn_ln, dim3(NG/16), dim3(256), 0, stream,
                     b_in, b_out, g2, o2, mV, ws, outp);
}

// Round 3
// 849.431 us; speedup vs baseline: 1.1836x; 1.0154x over previous
//
#include <hip/hip_runtime.h>
#include <hip/hip_bf16.h>

typedef unsigned short u16;
typedef __attribute__((ext_vector_type(8))) short short8;
typedef __attribute__((ext_vector_type(4))) float f32x4;

#define SD   128
#define SNIN 384
#define SK   48
#define FPAD 520   // 512+8 elems (ffn_ln LDS row stride)

// ws layout (bytes) — packed bf16 weights only (448 KB total)
#define OFF_W1A   0
#define OFF_W1B   32768
#define OFF_W2    131072
#define OFF_W3    163840
#define OFF_WIN   196608
#define OFF_WOUT  327680

__device__ __forceinline__ u16 f2b(float f){
  union { float f; unsigned u; } v; v.f = f;
  unsigned r = (v.u + 0x7FFFu + ((v.u >> 16) & 1u)) >> 16;   // RNE
  return (u16)r;
}
__device__ __forceinline__ short8 ldg8(const u16* p){
  return *reinterpret_cast<const short8*>(p);
}
// pack 8 fp32 (two float4) -> bf16x8 via v_cvt_pk_bf16_f32 (RNE, 4 instrs)
__device__ __forceinline__ short8 pack8(float4 a, float4 b){
  union { unsigned u[4]; short8 s; } r;
  asm("v_cvt_pk_bf16_f32 %0, %1, %2" : "=v"(r.u[0]) : "v"(a.x), "v"(a.y));
  asm("v_cvt_pk_bf16_f32 %0, %1, %2" : "=v"(r.u[1]) : "v"(a.z), "v"(a.w));
  asm("v_cvt_pk_bf16_f32 %0, %1, %2" : "=v"(r.u[2]) : "v"(b.x), "v"(b.y));
  asm("v_cvt_pk_bf16_f32 %0, %1, %2" : "=v"(r.u[3]) : "v"(b.z), "v"(b.w));
  return r.s;
}
__device__ __forceinline__ short8 cvt8(const float* p){
  float4 a = *reinterpret_cast<const float4*>(p);
  float4 b = *reinterpret_cast<const float4*>(p + 4);
  return pack8(a, b);
}

// gelu(x)=0.5*x*(1+erf(x/sqrt2)); odd deg-7 poly of erf on [-3,3], clamped. abs err < 7e-3.
__device__ __forceinline__ float gelu_f(float x){
  float xc = fminf(3.0f, fmaxf(-3.0f, x));
  float u  = xc*xc;
  float p  = fmaf(u, fmaf(u, fmaf(u, -4.81034e-4f, 1.185750e-2f), -1.1877797e-1f), 7.9165011e-1f);
  float t  = xc*p;
  float hx = 0.5f*x;
  return fmaf(t, hx, hx);
}

// ---------------- prep: fp32 weights -> bf16 MFMA B-fragment-linear layout ----------------
// B-frag (16x16x32): lane holds B[k=(lane>>4)*8+j][n=nt*16+(lane&15)], j=0..7.
// Frag order: ((ks*NT + nt)*64 + lane)*8 elems -> 16B contiguous per lane.
__global__ __launch_bounds__(256) void prep_pack(
    const float* __restrict__ W1, const float* __restrict__ W2, const float* __restrict__ W3,
    const float* __restrict__ Win, const float* __restrict__ Wout, u16* __restrict__ ws)
{
  int t = blockIdx.x*256 + threadIdx.x;   // 28672 frag-lanes total
  const float* src; int stride, rowoff, NT; u16* dst; int local;
  if (t < 2048)       { src=W1;  stride=SD;  rowoff=0;   NT=8;  dst=ws+OFF_W1A/2;  local=t;       }
  else if (t < 8192)  { src=W1;  stride=SD;  rowoff=128; NT=8;  dst=ws+OFF_W1B/2;  local=t-2048;  }
  else if (t < 10240) { src=W2;  stride=SD;  rowoff=0;   NT=8;  dst=ws+OFF_W2/2;   local=t-8192;  }
  else if (t < 12288) { src=W3;  stride=SD;  rowoff=0;   NT=8;  dst=ws+OFF_W3/2;   local=t-10240; }
  else if (t < 20480) { src=Win; stride=512; rowoff=0;   NT=32; dst=ws+OFF_WIN/2;  local=t-12288; }
  else                { src=Wout;stride=SD;  rowoff=0;   NT=8;  dst=ws+OFF_WOUT/2; local=t-20480; }
  int lane = local & 63;
  int blk  = local >> 6;
  int nt = blk % NT, ks = blk / NT;
  int k0 = rowoff + ks*32 + (lane>>4)*8;
  int n  = nt*16 + (lane & 15);
  union { u16 a[8]; short8 v; } tmp;
  #pragma unroll
  for (int j=0;j<8;j++) tmp.a[j] = f2b(src[(size_t)(k0+j)*stride + n]);
  *reinterpret_cast<short8*>(dst + (size_t)local*8) = tmp.v;
}

// ---------------- kernel A: one BLOCK per node (4 waves cooperate) ----------------
// hE (48x384 fp32, 72KB) is streamed SEQUENTIALLY (each wave reads 2KB-contiguous spans,
// block reads its 72KB front-to-back -> DRAM row-buffer friendly), converted fp32->bf16
// once at staging (RNE, same values as before), and written to LDS with a per-row XOR
// granule swizzle (reg-staging allows swizzled dest). G1 is then a barrier-free LDS+MFMA
// K-loop with W1B prefetched 1 ks ahead from L2. The 36KB hE buffer is reused for H1/H2.
__global__ __launch_bounds__(256, 4) void dec_nodes(
    const float* __restrict__ hV, const float* __restrict__ hE, const float* __restrict__ mAtt,
    const float* __restrict__ b1, const float* __restrict__ b2, const float* __restrict__ b3,
    const float* __restrict__ g1, const float* __restrict__ o1,
    const u16* __restrict__ ws, float* __restrict__ u_out)
{
  __shared__ __align__(16) u16 HEs[48*384];   // 36KB: hE as bf16 (swizzled); later H1/H2
  __shared__ float LNS[8];

  const int tid  = threadIdx.x;
  const int w    = tid >> 6;
  const int lane = tid & 63;
  const int quad = lane >> 4;
  const int l16  = lane & 15;
  const int g    = blockIdx.x;     // this block's node
  const int n0   = w*2;            // this wave's first nt tile (cols n0*16 .. n0*16+31)

  // ---- sequential reg-staging of hE: 2304 granules (16B bf16 = 8 fp32 = 32B src), 9/thread
  // granule G: r=G/48 (row), c=G%48 (16B-col); LDS phys granule = c ^ (r&7) (bank spread)
  const float* hEn = hE + (size_t)g*(SK*SNIN);
  #define SLD3(s0, RA, RB) { _Pragma("unroll") for (int q=0;q<3;q++){ int G=((s0)+q)*256+tid; \
      RA[q] = *reinterpret_cast<const float4*>(hEn + (size_t)G*8); \
      RB[q] = *reinterpret_cast<const float4*>(hEn + (size_t)G*8 + 4); } }
  #define SWR3(s0, RA, RB) { _Pragma("unroll") for (int q=0;q<3;q++){ int G=((s0)+q)*256+tid; \
      int r = G/48, c = G - r*48; \
      *reinterpret_cast<short8*>(HEs + r*384 + ((c ^ (r&7))<<3)) = pack8(RA[q], RB[q]); } }
  {
    float4 ra[3], rb[3], rc[3], rd[3];
    SLD3(0, ra, rb);
    SLD3(3, rc, rd);
    SWR3(0, ra, rb);
    SLD3(6, ra, rb);
    SWR3(3, rc, rd);
    SWR3(6, ra, rb);
  }

  // ---- base1[j] = (hV[g] @ W1[:128])[col] + b1[col], col=(n0+j)*16+l16, broadcast-A MFMA
  float base1v[2];
  {
    f32x4 accb[2] = {(f32x4){0.f,0.f,0.f,0.f},(f32x4){0.f,0.f,0.f,0.f}};
    const float* hp = hV + (size_t)g*SD + quad*8;
    const u16* Bb1 = ws + OFF_W1A/2 + (size_t)lane*8;
    #pragma unroll
    for (int ks=0; ks<4; ks++){
      short8 af = cvt8(hp + ks*32);
      #pragma unroll
      for (int j=0;j<2;j++){
        short8 bf = ldg8(Bb1 + ((size_t)(ks*8 + n0 + j)*64)*8);
        accb[j] = __builtin_amdgcn_mfma_f32_16x16x32_bf16(af, bf, accb[j], 0,0,0);
      }
    }
    #pragma unroll
    for (int j=0;j<2;j++) base1v[j] = accb[j][0] + b1[(n0+j)*16 + l16];
  }
  __syncthreads();   // all staging writes visible to all waves

  // ---- G1: H1 = gelu(hE @ W1[128:] + base1); no barriers in K-loop
  f32x4 acc[3][2];
  #pragma unroll
  for (int mt=0;mt<3;mt++){ acc[mt][0]=(f32x4){0.f,0.f,0.f,0.f}; acc[mt][1]=(f32x4){0.f,0.f,0.f,0.f}; }
  {
    const u16* BbG1 = ws + OFF_W1B/2 + (size_t)lane*8;
    short8 bq0 = ldg8(BbG1 + ((size_t)(n0)*64)*8);
    short8 bq1 = ldg8(BbG1 + ((size_t)(n0+1)*64)*8);
    #pragma unroll
    for (int ks=0; ks<12; ks++){
      short8 bn0, bn1;
      if (ks < 11){
        bn0 = ldg8(BbG1 + ((size_t)((ks+1)*8 + n0)*64)*8);
        bn1 = ldg8(BbG1 + ((size_t)((ks+1)*8 + n0+1)*64)*8);
      }
      #pragma unroll
      for (int mt=0;mt<3;mt++){
        int row = mt*16 + l16;
        short8 af = *reinterpret_cast<const short8*>(
                      HEs + row*384 + (((ks*4 + quad) ^ (row&7))<<3));
        acc[mt][0] = __builtin_amdgcn_mfma_f32_16x16x32_bf16(af, bq0, acc[mt][0], 0,0,0);
        acc[mt][1] = __builtin_amdgcn_mfma_f32_16x16x32_bf16(af, bq1, acc[mt][1], 0,0,0);
      }
      if (ks < 11){ bq0 = bn0; bq1 = bn1; }
    }
  }
  __syncthreads();   // all hE reads done; HEs region reusable as H buffer

  // H1 -> HEs (H layout: row stride 128 u16, phys slot16 = (col>>3) ^ (row&15))
  #pragma unroll
  for (int mt=0; mt<3; mt++)
    #pragma unroll
    for (int j=0; j<2; j++)
      #pragma unroll
      for (int i=0;i<4;i++){
        int row = mt*16 + quad*4 + i;
        int col = (n0+j)*16 + l16;
        HEs[row*128 + (((col>>3) ^ (row&15))<<3) + (col&7)] = f2b(gelu_f(acc[mt][j][i] + base1v[j]));
      }
  __syncthreads();

  // ---- G2: H2 = gelu(H1 @ W2 + b2)
  #pragma unroll
  for (int mt=0;mt<3;mt++){ acc[mt][0]=(f32x4){0.f,0.f,0.f,0.f}; acc[mt][1]=(f32x4){0.f,0.f,0.f,0.f}; }
  {
    const u16* Bb = ws + OFF_W2/2 + (size_t)lane*8;
    #pragma unroll
    for (int ks=0; ks<4; ks++){
      short8 afm[3];
      #pragma unroll
      for (int mt=0; mt<3; mt++){
        int row = mt*16 + l16;
        int sp  = (ks*4 + quad) ^ l16;
        afm[mt] = *reinterpret_cast<const short8*>(HEs + row*128 + sp*8);
      }
      #pragma unroll
      for (int j=0;j<2;j++){
        short8 bf = ldg8(Bb + ((size_t)(ks*8 + n0 + j)*64)*8);
        #pragma unroll
        for (int mt=0;mt<3;mt++)
          acc[mt][j] = __builtin_amdgcn_mfma_f32_16x16x32_bf16(afm[mt], bf, acc[mt][j], 0,0,0);
      }
    }
  }
  __syncthreads();   // all H1 reads done before overwrite
  #pragma unroll
  for (int mt=0; mt<3; mt++)
    #pragma unroll
    for (int j=0; j<2; j++){
      float bb = b2[(n0+j)*16 + l16];
      #pragma unroll
      for (int i=0;i<4;i++){
        int row = mt*16 + quad*4 + i;
        int col = (n0+j)*16 + l16;
        HEs[row*128 + (((col>>3) ^ (row&15))<<3) + (col&7)] = f2b(gelu_f(acc[mt][j][i] + bb));
      }
    }
  __syncthreads();

  // ---- G3: M = H2 @ W3 + b3; dh[col] = sum_k mask[k]*M[k][col]
  #pragma unroll
  for (int mt=0;mt<3;mt++){ acc[mt][0]=(f32x4){0.f,0.f,0.f,0.f}; acc[mt][1]=(f32x4){0.f,0.f,0.f,0.f}; }
  {
    const u16* Bb = ws + OFF_W3/2 + (size_t)lane*8;
    #pragma unroll
    for (int ks=0; ks<4; ks++){
      short8 afm[3];
      #pragma unroll
      for (int mt=0; mt<3; mt++){
        int row = mt*16 + l16;
        int sp  = (ks*4 + quad) ^ l16;
        afm[mt] = *reinterpret_cast<const short8*>(HEs + row*128 + sp*8);
      }
      #pragma unroll
      for (int j=0;j<2;j++){
        short8 bf = ldg8(Bb + ((size_t)(ks*8 + n0 + j)*64)*8);
        #pragma unroll
        for (int mt=0;mt<3;mt++)
          acc[mt][j] = __builtin_amdgcn_mfma_f32_16x16x32_bf16(afm[mt], bf, acc[mt][j], 0,0,0);
      }
    }
  }
  float p0 = 0.f, p1 = 0.f;
  {
    float b3v0 = b3[(n0)*16 + l16], b3v1 = b3[(n0+1)*16 + l16];
    #pragma unroll
    for (int mt=0; mt<3; mt++)
      #pragma unroll
      for (int i=0;i<4;i++){
        float m = mAtt[(size_t)g*SK + mt*16 + quad*4 + i];
        p0 = fmaf(m, acc[mt][0][i] + b3v0, p0);
        p1 = fmaf(m, acc[mt][1][i] + b3v1, p1);
      }
    p0 += __shfl_down(p0, 32, 64); p0 += __shfl_down(p0, 16, 64); p0 = __shfl(p0, l16, 64);
    p1 += __shfl_down(p1, 32, 64); p1 += __shfl_down(p1, 16, 64); p1 = __shfl(p1, l16, 64);
  }

  // ---- LN1 (cross-wave via LDS; each col counted 4x across quads -> /512)
  {
    float x0 = hV[(size_t)g*SD + (n0)*16   + l16] + p0*(1.0f/30.0f);
    float x1 = hV[(size_t)g*SD + (n0+1)*16 + l16] + p1*(1.0f/30.0f);
    float s = x0 + x1;
    float q = fmaf(x0, x0, x1*x1);
    #pragma unroll
    for (int off=1; off<64; off<<=1){ s += __shfl_xor(s, off, 64); q += __shfl_xor(q, off, 64); }
    if (lane == 0){ LNS[w] = s; LNS[4+w] = q; }
    __syncthreads();
    s = LNS[0]+LNS[1]+LNS[2]+LNS[3];
    q = LNS[4]+LNS[5]+LNS[6]+LNS[7];
    float mu  = s * (1.0f/512.0f);
    float var = q * (1.0f/512.0f) - mu*mu;
    float rs  = rsqrtf(var + 1e-5f);
    if (quad == 0){
      int c0 = (n0)*16 + l16, c1 = (n0+1)*16 + l16;
      u_out[(size_t)g*SD + c0] = (x0-mu)*rs*g1[c0] + o1[c0];
      u_out[(size_t)g*SD + c1] = (x1-mu)*rs*g1[c1] + o1[c1];
    }
  }
  #undef SLD3
  #undef SWR3
}

// ---------------- kernel B: batched FFN + residual + LN2 + mask_V (in-place on d_out) --------
// 512 blocks x 256 thr (4 waves), 16 rows/block; FFN1 split by N (wave w: cols w*128..),
// FFN2 split by N (wave w: col tiles 2w,2w+1), LN2 via fp32 LDS exchange.
__global__ __launch_bounds__(256) void ffn_ln(
    const float* __restrict__ b_in, const float* __restrict__ b_out,
    const float* __restrict__ g2, const float* __restrict__ o2, const float* __restrict__ mV,
    const u16* __restrict__ ws, float* __restrict__ uo)
{
  __shared__ u16 fS[16*FPAD];
  __shared__ float dS[16][132];
  const int tid = threadIdx.x, w = tid>>6, lane = tid&63, quad = lane>>4, l16 = lane&15;
  const int m0 = blockIdx.x*16;

  // A-frags for rows m0..m0+15 (same for all 4 waves)
  short8 afr[4];
  const float* Ap = uo + (size_t)(m0 + l16)*SD + quad*8;
  #pragma unroll
  for (int ks=0; ks<4; ks++) afr[ks] = cvt8(Ap + ks*32);

  // FFN1: wave w computes f cols [w*128, w*128+128)
  {
    f32x4 acc[8];
    #pragma unroll
    for (int t=0;t<8;t++) acc[t] = (f32x4){0.f,0.f,0.f,0.f};
    const u16* Bp = ws + OFF_WIN/2 + ((size_t)(w*8)*64 + lane)*8;
    #pragma unroll
    for (int ks=0; ks<4; ks++){
      #pragma unroll
      for (int t=0;t<8;t++){
        short8 bf = ldg8(Bp + ((size_t)ks*32 + t)*512);
        acc[t] = __builtin_amdgcn_mfma_f32_16x16x32_bf16(afr[ks], bf, acc[t], 0,0,0);
      }
    }
    #pragma unroll
    for (int t=0;t<8;t++){
      int coln = w*128 + t*16 + l16;
      float bi = b_in[coln];
      #pragma unroll
      for (int i=0;i<4;i++)
        fS[(quad*4+i)*FPAD + coln] = f2b(gelu_f(acc[t][i] + bi));
    }
  }
  __syncthreads();

  // FFN2: wave w computes dh2 col tiles 2w, 2w+1 over full K=512
  {
    f32x4 acc2[2];
    acc2[0] = (f32x4){0.f,0.f,0.f,0.f};
    acc2[1] = (f32x4){0.f,0.f,0.f,0.f};
    const u16* Bo = ws + OFF_WOUT/2 + (size_t)lane*8;
    #pragma unroll
    for (int ks=0; ks<16; ks++){
      const short8 af = *reinterpret_cast<const short8*>(&fS[l16*FPAD + ks*32 + quad*8]);
      #pragma unroll
      for (int j=0;j<2;j++){
        short8 bf = ldg8(Bo + ((size_t)ks*8 + (w*2+j))*512);
        acc2[j] = __builtin_amdgcn_mfma_f32_16x16x32_bf16(af, bf, acc2[j], 0,0,0);
      }
    }
    #pragma unroll
    for (int j=0;j<2;j++){
      int cl = (w*2+j)*16 + l16;
      float bo = b_out[cl];
      #pragma unroll
      for (int i=0;i<4;i++)
        dS[quad*4+i][cl] = acc2[j][i] + bo;
    }
  }
  __syncthreads();

  // residual + LN2 + mask_V for row r = m0 + w*4 + quad
  {
    int rl = w*4 + quad;
    int r  = m0 + rl;
    float xv[8]; float s = 0.f, q = 0.f;
    #pragma unroll
    for (int t=0;t<8;t++){
      xv[t] = uo[(size_t)r*SD + t*16 + l16] + dS[rl][t*16 + l16];
      s += xv[t]; q = fmaf(xv[t], xv[t], q);
    }
    #pragma unroll
    for (int mk=1; mk<16; mk<<=1){ s += __shfl_xor(s, mk, 64); q += __shfl_xor(q, mk, 64); }
    float mu  = s * (1.0f/128.0f);
    float var = q * (1.0f/128.0f) - mu*mu;
    float rs  = rsqrtf(var + 1e-5f);
    float mv  = mV[r];
    #pragma unroll
    for (int t=0;t<8;t++){
      int cl = t*16 + l16;
      uo[(size_t)r*SD + cl] = mv * ((xv[t]-mu)*rs*g2[cl] + o2[cl]);
    }
  }
}

extern "C" void kernel_launch(void* const* d_in, const int* in_sizes, int n_in,
                              void* d_out, int out_size, void* d_ws, size_t ws_size,
                              hipStream_t stream) {
  (void)n_in; (void)out_size; (void)ws_size;
  const float* hV    = (const float*)d_in[0];
  const float* hE    = (const float*)d_in[1];
  const float* mV    = (const float*)d_in[2];
  const float* mAtt  = (const float*)d_in[3];
  const float* W1    = (const float*)d_in[4];
  const float* b1    = (const float*)d_in[5];
  const float* W2    = (const float*)d_in[6];
  const float* b2    = (const float*)d_in[7];
  const float* W3    = (const float*)d_in[8];
  const float* b3    = (const float*)d_in[9];
  const float* Win   = (const float*)d_in[10];
  const float* b_in  = (const float*)d_in[11];
  const float* Wout  = (const float*)d_in[12];
  const float* b_out = (const float*)d_in[13];
  const float* g1    = (const float*)d_in[14];
  const float* o1    = (const float*)d_in[15];
  const float* g2    = (const float*)d_in[16];
  const float* o2    = (const float*)d_in[17];
  u16*   ws   = (u16*)d_ws;
  float* outp = (float*)d_out;
  const int NG = in_sizes[0] / SD;   // 8192 nodes

  hipLaunchKernelGGL(prep_pack, dim3(112), dim3(256), 0, stream, W1, W2, W3, Win, Wout, ws);
  hipLaunchKernelGGL(dec_nodes, dim3(NG), dim3(256), 0, stream,
                     hV, hE, mAtt, b1, b2, b3, g1, o1, ws, outp);
  hipLaunchKernelGGL(ffn_ln, dim3(NG/16), dim3(256), 0, stream,
                     b_in, b_out, g2, o2, mV, ws, outp);
}